// Round 10
// baseline (263.963 us; speedup 1.0000x reference)
//
#include <hip/hip_runtime.h>
#include <math.h>

typedef _Float16 f16;
typedef _Float16 f16x8 __attribute__((ext_vector_type(8)));
typedef float f32x16 __attribute__((ext_vector_type(16)));

#define MFMA_ __builtin_amdgcn_mfma_f32_32x32x16_f16
#define SLOPE_ 0.2f

constexpr int kB = 64, kT = 512, kD = 8, kH = 128, kE = 96;
constexpr int kFG = 145, kTM = 510, kN = kB * kTM;   // 32640 = 255*128

// k-permutation absorbed into weight images so next-layer B-fragments are the
// held C/D quads verbatim: pi(16c+8s+j) = 32(c>>1)+16(c&1)+8(j>>2)+4s+(j&3)
__device__ __forceinline__ int pif(int k) {
  if (k >= 128) return k;                     // g L0 yy region stays canonical
  int c = k >> 4, s = (k >> 3) & 1, j = k & 7;
  return ((c >> 1) << 5) | ((c & 1) << 4) | ((j >> 2) << 3) | (s << 2) | (j & 3);
}

// fragment-linear images: frag f = 64 lanes x 16 B contiguous.
__device__ __forceinline__ f16x8 gfrag(const f16* img, int f, int lane) {
  return *(const f16x8*)(img + f*512 + lane*8);
}

// ========= weight pre-convert: f32 row-major -> f16 fragment-linear =========
template<int NF, int SK, int PERM>
__device__ __forceinline__ void cvt_img(const float* __restrict__ src,
                                        f16* __restrict__ dst, int nd,
                                        int t0, int stride) {
  const int per_d = NF * 512;
  for (int e = t0; e < nd * per_d; e += stride) {
    int dd = e / per_d, r = e - dd * per_d;
    int f = r >> 9, l = (r >> 3) & 63, j = r & 7;
    int c = f >> 2, t = f & 3;
    int row = t*32 + (l & 31);
    int col = c*16 + ((l >> 5) << 3) + j;
    if (PERM) col = pif(col);
    dst[e] = (f16)src[((size_t)dd*kH + row)*SK + col];
  }
}

__global__ __launch_bounds__(256) void cvt_kernel(
    const float* __restrict__ gW0, const float* __restrict__ gW1,
    const float* __restrict__ gW2,
    const float* __restrict__ fcW0, const float* __restrict__ fcW1,
    const float* __restrict__ fcWf,
    f16* __restrict__ W0img, f16* __restrict__ W1img, f16* __restrict__ W2img,
    f16* __restrict__ fW0img, f16* __restrict__ fW1img, f16* __restrict__ fWfimg,
    float* __restrict__ w144buf, float* __restrict__ logdet)
{
  const int stride = gridDim.x * 256;
  const int t0 = blockIdx.x*256 + threadIdx.x;
  cvt_img<36, kFG, 1>(gW0, W0img, kD, t0, stride);
  cvt_img<32, kH , 1>(gW1, W1img, kD, t0, stride);
  cvt_img<32, kH , 1>(gW2, W2img, kD, t0, stride);
  cvt_img<24, kE , 0>(fcW0, fW0img, 1, t0, stride);
  cvt_img<32, kH , 1>(fcW1, fW1img, 1, t0, stride);
  cvt_img<32, kH , 1>(fcWf, fWfimg, 1, t0, stride);
  for (int i = t0; i < kD*kH; i += stride)
    w144buf[i] = gW0[(size_t)i*kFG + 144];
  if (t0 < kB) logdet[t0] = 0.f;
}

// ===== fc_mlp: emb(N,96) -> embh'(N,128) f16 (pi-ordered) ===================
__global__ __launch_bounds__(256, 3) void fc_kernel(
    const float* __restrict__ emb,
    const f16* __restrict__ fW0, const f16* __restrict__ fW1,
    const f16* __restrict__ fWf,
    const float* __restrict__ b0, const float* __restrict__ b1,
    const float* __restrict__ bf, f16* __restrict__ out)
{
  __shared__ f16 wbuf[32*512];                 // fW1 frags, 32 KB
  const int bn = blockIdx.x * 128;
  const int tid = threadIdx.x, wave = tid >> 6, lane = tid & 63;
  const int l31 = lane & 31, h5 = lane >> 5;
  const int n = bn + wave*32 + l31;

  #pragma unroll
  for (int i = 0; i < 8; ++i)                  // 2048 f16x8 units exactly
    *(f16x8*)(wbuf + (size_t)(tid + i*256)*8) =
        *(const f16x8*)(fW1 + (size_t)(tid + i*256)*8);

  f32x16 zero = {};
  f32x16 acc[4] = {zero, zero, zero, zero};
  const float* erow = emb + (size_t)n*kE + h5*8;
  #pragma unroll
  for (int c = 0; c < 6; ++c) {
    float4 a = *(const float4*)(erow + c*16);
    float4 bb = *(const float4*)(erow + c*16 + 4);
    f16x8 v;
    v[0]=(f16)a.x; v[1]=(f16)a.y; v[2]=(f16)a.z; v[3]=(f16)a.w;
    v[4]=(f16)bb.x; v[5]=(f16)bb.y; v[6]=(f16)bb.z; v[7]=(f16)bb.w;
    #pragma unroll
    for (int t = 0; t < 4; ++t)
      acc[t] = MFMA_(gfrag(fW0, c*4+t, lane), v, acc[t], 0, 0, 0);
  }

  f16x8 hq[4][2];
  #pragma unroll
  for (int t = 0; t < 4; ++t)
    #pragma unroll
    for (int q = 0; q < 4; ++q) {
      float4 b4 = *(const float4*)(b0 + t*32 + q*8 + h5*4);
      const float* bp = (const float*)&b4;
      #pragma unroll
      for (int e = 0; e < 4; ++e) {
        float z = acc[t][q*4+e] + bp[e];
        hq[t][q>>1][(q&1)*4+e] = (f16)fmaxf(z, SLOPE_*z);
      }
    }
  __syncthreads();                              // B1: wbuf ready

  #pragma unroll
  for (int t = 0; t < 4; ++t) acc[t] = zero;
  #pragma unroll
  for (int c = 0; c < 8; ++c) {
    f16x8 bP = hq[c>>1][c&1];
    #pragma unroll
    for (int t = 0; t < 4; ++t)
      acc[t] = MFMA_(*(const f16x8*)(wbuf + (size_t)(c*4+t)*512 + lane*8),
                     bP, acc[t], 0, 0, 0);
  }
  #pragma unroll
  for (int t = 0; t < 4; ++t)
    #pragma unroll
    for (int q = 0; q < 4; ++q) {
      float4 b4 = *(const float4*)(b1 + t*32 + q*8 + h5*4);
      const float* bp = (const float*)&b4;
      #pragma unroll
      for (int e = 0; e < 4; ++e) {
        float z = acc[t][q*4+e] + bp[e];
        hq[t][q>>1][(q&1)*4+e] = (f16)fmaxf(z, SLOPE_*z);
      }
    }

  #pragma unroll
  for (int t = 0; t < 4; ++t) acc[t] = zero;
  #pragma unroll
  for (int c = 0; c < 8; ++c) {
    f16x8 bP = hq[c>>1][c&1];
    #pragma unroll
    for (int t = 0; t < 4; ++t)
      acc[t] = MFMA_(gfrag(fWf, c*4+t, lane), bP, acc[t], 0, 0, 0);
  }
  #pragma unroll
  for (int t = 0; t < 4; ++t)
    #pragma unroll
    for (int q = 0; q < 4; ++q) {
      float4 b4 = *(const float4*)(bf + t*32 + q*8 + h5*4);
      const float* bp = (const float*)&b4;
      #pragma unroll
      for (int e = 0; e < 4; ++e)
        hq[t][q>>1][(q&1)*4+e] = (f16)(acc[t][q*4+e] + bp[e]);
    }
  #pragma unroll
  for (int c = 0; c < 8; ++c)
    *(f16x8*)(out + (size_t)n*kH + c*16 + h5*8) = hq[c>>1][c&1];
}

// ==== g_mlp fwd + JVP: sequential P-then-T per wave, masks in registers =====
// Block = 128 rows x one d, 4 waves x 32 rows x all cols. acc[4] (64 AGPR)
// and hq reused across both phases; uniform control flow (no spill paths).
__global__ __launch_bounds__(256, 3) void g_kernel(
    const float* __restrict__ x, const f16* __restrict__ embh,
    const f16* __restrict__ W0img, const f16* __restrict__ W1img,
    const f16* __restrict__ W2img,
    const float* __restrict__ w144buf,
    const float* __restrict__ gb0, const float* __restrict__ gb1,
    const float* __restrict__ gb2, const float* __restrict__ gWf,
    const float* __restrict__ gbf,
    float* __restrict__ resid, float* __restrict__ logdet)
{
  __shared__ f16 wbuf[32*512];                 // W1 frags, 32 KB
  __shared__ float part[8];
  const int d = blockIdx.y, bx = blockIdx.x, bn = bx*128;
  const int tid = threadIdx.x, wave = tid >> 6, lane = tid & 63;
  const int l31 = lane & 31, h5 = lane >> 5;
  const int n = bn + wave*32 + l31;
  const int b = n / kTM, tt = n - b*kTM;

  const f16* W0d = W0img + d*36*512;
  const f16* W1d = W1img + d*32*512;
  const f16* W2d = W2img + d*32*512;

  // stage W1 (exactly 2048 f16x8 units)
  #pragma unroll
  for (int i = 0; i < 8; ++i)
    *(f16x8*)(wbuf + (size_t)(tid + i*256)*8) =
        *(const f16x8*)(W1d + (size_t)(tid + i*256)*8);

  // x-derived inputs
  const float* xp = x + ((size_t)b*kT + tt + h5)*kD;
  float4 xa = *(const float4*)xp;
  float4 xb = *(const float4*)(xp + 4);
  f16x8 f8;
  f8[0]=(f16)xa.x; f8[1]=(f16)xa.y; f8[2]=(f16)xa.z; f8[3]=(f16)xa.w;
  f8[4]=(f16)xb.x; f8[5]=(f16)xb.y; f8[6]=(f16)xb.z; f8[7]=(f16)xb.w;
  const float xxv = x[((size_t)b*kT + tt + 2)*kD + d];

  f32x16 zero = {};
  f32x16 acc[4] = {zero, zero, zero, zero};

  // ---- P L0 (W0 direct-global)
  const f16* erow = embh + (size_t)n*kH + h5*8;
  #pragma unroll
  for (int c = 0; c < 8; ++c) {
    f16x8 eF = *(const f16x8*)(erow + c*16);
    #pragma unroll
    for (int t = 0; t < 4; ++t)
      acc[t] = MFMA_(gfrag(W0d, c*4+t, lane), eF, acc[t], 0, 0, 0);
  }
  #pragma unroll
  for (int t = 0; t < 4; ++t)
    acc[t] = MFMA_(gfrag(W0d, 32+t, lane), f8, acc[t], 0, 0, 0);

  f16x8 hq[4][2];
  unsigned mk0[4], mk1[4], mk2[4];
  #pragma unroll
  for (int t = 0; t < 4; ++t) {
    unsigned bits = 0;
    #pragma unroll
    for (int q = 0; q < 4; ++q) {
      float4 w4 = *(const float4*)(w144buf + d*kH + t*32 + q*8 + h5*4);
      float4 b4 = *(const float4*)(gb0 + d*kH + t*32 + q*8 + h5*4);
      const float* wp = (const float*)&w4;
      const float* bp = (const float*)&b4;
      #pragma unroll
      for (int e = 0; e < 4; ++e) {
        float z = acc[t][q*4+e] + xxv*wp[e] + bp[e];
        bool pos = (z >= 0.f);
        bits |= (unsigned)pos << (q*4+e);
        hq[t][q>>1][(q&1)*4+e] = (f16)(pos ? z : SLOPE_*z);
      }
    }
    mk0[t] = bits;
  }
  __syncthreads();                              // B1: wbuf ready (after L0)

  // ---- P L1 (LDS)
  #pragma unroll
  for (int t = 0; t < 4; ++t) acc[t] = zero;
  #pragma unroll
  for (int c = 0; c < 8; ++c) {
    f16x8 bP = hq[c>>1][c&1];
    #pragma unroll
    for (int t = 0; t < 4; ++t)
      acc[t] = MFMA_(*(const f16x8*)(wbuf + (size_t)(c*4+t)*512 + lane*8),
                     bP, acc[t], 0, 0, 0);
  }
  #pragma unroll
  for (int t = 0; t < 4; ++t) {
    unsigned bits = 0;
    #pragma unroll
    for (int q = 0; q < 4; ++q) {
      float4 b4 = *(const float4*)(gb1 + d*kH + t*32 + q*8 + h5*4);
      const float* bp = (const float*)&b4;
      #pragma unroll
      for (int e = 0; e < 4; ++e) {
        float z = acc[t][q*4+e] + bp[e];
        bool pos = (z >= 0.f);
        bits |= (unsigned)pos << (q*4+e);
        hq[t][q>>1][(q&1)*4+e] = (f16)(pos ? z : SLOPE_*z);
      }
    }
    mk1[t] = bits;
  }

  // ---- P L2 (W2 direct-global) + resid
  #pragma unroll
  for (int t = 0; t < 4; ++t) acc[t] = zero;
  #pragma unroll
  for (int c = 0; c < 8; ++c) {
    f16x8 bP = hq[c>>1][c&1];
    #pragma unroll
    for (int t = 0; t < 4; ++t)
      acc[t] = MFMA_(gfrag(W2d, c*4+t, lane), bP, acc[t], 0, 0, 0);
  }
  float p = 0.f;
  #pragma unroll
  for (int t = 0; t < 4; ++t) {
    unsigned bits = 0;
    #pragma unroll
    for (int q = 0; q < 4; ++q) {
      float4 b4 = *(const float4*)(gb2 + d*kH + t*32 + q*8 + h5*4);
      float4 w4 = *(const float4*)(gWf + d*kH + t*32 + q*8 + h5*4);
      const float* bp = (const float*)&b4;
      const float* wp = (const float*)&w4;
      #pragma unroll
      for (int e = 0; e < 4; ++e) {
        float z = acc[t][q*4+e] + bp[e];
        bool pos = (z >= 0.f);
        bits |= (unsigned)pos << (q*4+e);
        p = fmaf(pos ? z : SLOPE_*z, wp[e], p);
      }
    }
    mk2[t] = bits;
  }
  p += __shfl_xor(p, 32, 64);
  if (!h5) resid[(size_t)n*kD + d] = p + gbf[d];

  // ---- T phase: t0 = m0 ? w144 : 0.2*w144
  #pragma unroll
  for (int t = 0; t < 4; ++t) {
    unsigned bits = mk0[t];
    #pragma unroll
    for (int q = 0; q < 4; ++q) {
      float4 w4 = *(const float4*)(w144buf + d*kH + t*32 + q*8 + h5*4);
      const float* wp = (const float*)&w4;
      #pragma unroll
      for (int e = 0; e < 4; ++e)
        hq[t][q>>1][(q&1)*4+e] =
            (f16)(((bits >> (q*4+e)) & 1) ? wp[e] : SLOPE_*wp[e]);
    }
  }
  // ---- T L1 (LDS, same frags)
  #pragma unroll
  for (int t = 0; t < 4; ++t) acc[t] = zero;
  #pragma unroll
  for (int c = 0; c < 8; ++c) {
    f16x8 bT = hq[c>>1][c&1];
    #pragma unroll
    for (int t = 0; t < 4; ++t)
      acc[t] = MFMA_(*(const f16x8*)(wbuf + (size_t)(c*4+t)*512 + lane*8),
                     bT, acc[t], 0, 0, 0);
  }
  #pragma unroll
  for (int t = 0; t < 4; ++t) {
    unsigned bits = mk1[t];
    #pragma unroll
    for (int q = 0; q < 4; ++q)
      #pragma unroll
      for (int e = 0; e < 4; ++e) {
        float tv = acc[t][q*4+e];
        hq[t][q>>1][(q&1)*4+e] =
            (f16)(((bits >> (q*4+e)) & 1) ? tv : SLOPE_*tv);
      }
  }
  // ---- T L2 (W2 direct-global, L1-hit re-read)
  #pragma unroll
  for (int t = 0; t < 4; ++t) acc[t] = zero;
  #pragma unroll
  for (int c = 0; c < 8; ++c) {
    f16x8 bT = hq[c>>1][c&1];
    #pragma unroll
    for (int t = 0; t < 4; ++t)
      acc[t] = MFMA_(gfrag(W2d, c*4+t, lane), bT, acc[t], 0, 0, 0);
  }
  float tp = 0.f;
  #pragma unroll
  for (int t = 0; t < 4; ++t) {
    unsigned bits = mk2[t];
    #pragma unroll
    for (int q = 0; q < 4; ++q) {
      float4 w4 = *(const float4*)(gWf + d*kH + t*32 + q*8 + h5*4);
      const float* wp = (const float*)&w4;
      #pragma unroll
      for (int e = 0; e < 4; ++e) {
        float tv = acc[t][q*4+e];
        tp = fmaf(((bits >> (q*4+e)) & 1) ? tv : SLOPE_*tv, wp[e], tp);
      }
    }
  }
  tp += __shfl_xor(tp, 32, 64);

  float llog = 0.f;
  if (!h5) llog = logf(fabsf(tp));
  const int bfirst = bn / kTM;
  float s0 = (b == bfirst) ? llog : 0.f;
  float s1 = llog - s0;
  #pragma unroll
  for (int off = 32; off > 0; off >>= 1) {
    s0 += __shfl_down(s0, off, 64);
    s1 += __shfl_down(s1, off, 64);
  }
  if (lane == 0) { part[wave*2] = s0; part[wave*2 + 1] = s1; }
  __syncthreads();                              // B2
  if (tid == 0) {
    float S0 = part[0] + part[2] + part[4] + part[6];
    float S1 = part[1] + part[3] + part[5] + part[7];
    atomicAdd(&logdet[bfirst], S0);
    if (S1 != 0.f) atomicAdd(&logdet[bfirst + 1], S1);
  }
}

extern "C" void kernel_launch(void* const* d_in, const int* in_sizes, int n_in,
                              void* d_out, int out_size, void* d_ws, size_t ws_size,
                              hipStream_t stream) {
  const float* x    = (const float*)d_in[0];
  const float* emb  = (const float*)d_in[1];
  const float* fcW0 = (const float*)d_in[2];
  const float* fcb0 = (const float*)d_in[3];
  const float* fcW1 = (const float*)d_in[4];
  const float* fcb1 = (const float*)d_in[5];
  const float* fcWf = (const float*)d_in[6];
  const float* fcbf = (const float*)d_in[7];
  const float* gW0  = (const float*)d_in[8];
  const float* gb0  = (const float*)d_in[9];
  const float* gW1  = (const float*)d_in[10];
  const float* gb1  = (const float*)d_in[11];
  const float* gW2  = (const float*)d_in[12];
  const float* gb2  = (const float*)d_in[13];
  const float* gWf  = (const float*)d_in[14];
  const float* gbf  = (const float*)d_in[15];
  float* out = (float*)d_out;
  float* logdet = out + (size_t)kN * kD;

  char* ws = (char*)d_ws;
  f16*   embh    = (f16*)ws;    ws += (size_t)kN*kH*2;
  f16*   W0img   = (f16*)ws;    ws += (size_t)kD*36*512*2;
  f16*   W1img   = (f16*)ws;    ws += (size_t)kD*32*512*2;
  f16*   W2img   = (f16*)ws;    ws += (size_t)kD*32*512*2;
  f16*   fW0img  = (f16*)ws;    ws += (size_t)24*512*2;
  f16*   fW1img  = (f16*)ws;    ws += (size_t)32*512*2;
  f16*   fWfimg  = (f16*)ws;    ws += (size_t)32*512*2;
  float* w144buf = (float*)ws;

  cvt_kernel<<<256, 256, 0, stream>>>(gW0, gW1, gW2, fcW0, fcW1, fcWf,
                                      W0img, W1img, W2img,
                                      fW0img, fW1img, fWfimg,
                                      w144buf, logdet);
  fc_kernel<<<kN/128, 256, 0, stream>>>(emb, fW0img, fW1img, fWfimg,
                                        fcb0, fcb1, fcbf, embh);
  g_kernel<<<dim3(kN/128, kD), 256, 0, stream>>>(
      x, embh, W0img, W1img, W2img, w144buf,
      gb0, gb1, gb2, gWf, gbf, out, logdet);
}

// Round 11
// 158.163 us; speedup vs baseline: 1.6689x; 1.6689x over previous
//
#include <hip/hip_runtime.h>
#include <math.h>

typedef _Float16 f16;
typedef _Float16 f16x8 __attribute__((ext_vector_type(8)));
typedef float f32x16 __attribute__((ext_vector_type(16)));

#define MFMA_ __builtin_amdgcn_mfma_f32_32x32x16_f16
#define SLOPE_ 0.2f

constexpr int kB = 64, kT = 512, kD = 8, kH = 128, kE = 96;
constexpr int kFG = 145, kTM = 510, kN = kB * kTM;   // 32640 = 255*128

// k-permutation absorbed into weight images so next-layer B-fragments are the
// held C/D quads verbatim: pi(16c+8s+j) = 32(c>>1)+16(c&1)+8(j>>2)+4s+(j&3)
__device__ __forceinline__ int pif(int k) {
  if (k >= 128) return k;
  int c = k >> 4, s = (k >> 3) & 1, j = k & 7;
  return ((c >> 1) << 5) | ((c & 1) << 4) | ((j >> 2) << 3) | (s << 2) | (j & 3);
}

// fragment-linear images: frag f = 64 lanes x 16 B contiguous.
__device__ __forceinline__ f16x8 gfrag(const f16* img, int f, int lane) {
  return *(const f16x8*)(img + (size_t)f*512 + lane*8);
}

// ========= weight pre-convert: f32 row-major -> f16 fragment-linear =========
template<int NF, int SK, int PERM>
__device__ __forceinline__ void cvt_img(const float* __restrict__ src,
                                        f16* __restrict__ dst, int nd,
                                        int t0, int stride) {
  const int per_d = NF * 512;
  for (int e = t0; e < nd * per_d; e += stride) {
    int dd = e / per_d, r = e - dd * per_d;
    int f = r >> 9, l = (r >> 3) & 63, j = r & 7;
    int c = f >> 2, t = f & 3;
    int row = t*32 + (l & 31);
    int col = c*16 + ((l >> 5) << 3) + j;
    if (PERM) col = pif(col);
    dst[e] = (f16)src[((size_t)dd*kH + row)*SK + col];
  }
}

__global__ __launch_bounds__(256) void cvt_kernel(
    const float* __restrict__ gW0, const float* __restrict__ gW1,
    const float* __restrict__ gW2,
    const float* __restrict__ gb0, const float* __restrict__ gb1,
    const float* __restrict__ gb2, const float* __restrict__ gWf,
    const float* __restrict__ fcW0, const float* __restrict__ fcW1,
    const float* __restrict__ fcWf,
    f16* __restrict__ W0img, f16* __restrict__ W1img, f16* __restrict__ W2img,
    f16* __restrict__ wfimg,
    f16* __restrict__ fW0img, f16* __restrict__ fW1img, f16* __restrict__ fWfimg,
    float* __restrict__ w144buf, float* __restrict__ logdet)
{
  const int stride = gridDim.x * 256;
  const int t0 = blockIdx.x*256 + threadIdx.x;

  // W0img: 40 frags/d. cols: 0..127 pi(gW0), 128..144 canonical gW0 (incl w144),
  // 145 = gb0, 146..159 = 0.
  for (int e = t0; e < kD*40*512; e += stride) {
    int dd = e / (40*512), r = e - dd*(40*512);
    int f = r >> 9, l = (r >> 3) & 63, j = r & 7;
    int c = f >> 2, t = f & 3;
    int row = t*32 + (l & 31);
    int col = c*16 + ((l >> 5) << 3) + j;
    float v;
    if (col < 128)      v = gW0[((size_t)dd*kH + row)*kFG + pif(col)];
    else if (col < 145) v = gW0[((size_t)dd*kH + row)*kFG + col];
    else if (col == 145) v = gb0[dd*kH + row];
    else                v = 0.f;
    W0img[e] = (f16)v;
  }
  // W1img/W2img: 36 frags/d. cols 0..127 pi(W), col 128 = bias, 129..143 = 0.
  for (int e = t0; e < kD*36*512; e += stride) {
    int dd = e / (36*512), r = e - dd*(36*512);
    int f = r >> 9, l = (r >> 3) & 63, j = r & 7;
    int c = f >> 2, t = f & 3;
    int row = t*32 + (l & 31);
    int col = c*16 + ((l >> 5) << 3) + j;
    float v1, v2;
    if (col < 128) {
      int pc = pif(col);
      v1 = gW1[((size_t)dd*kH + row)*kH + pc];
      v2 = gW2[((size_t)dd*kH + row)*kH + pc];
    } else if (col == 128) {
      v1 = gb1[dd*kH + row];
      v2 = gb2[dd*kH + row];
    } else { v1 = 0.f; v2 = 0.f; }
    W1img[e] = (f16)v1;
    W2img[e] = (f16)v2;
  }
  // wfimg: 8 frags/d, wf in output-row 0 only, pi-ordered cols.
  for (int e = t0; e < kD*8*512; e += stride) {
    int dd = e >> 12, r = e & 4095;
    int f = r >> 9, l = (r >> 3) & 63, j = r & 7;
    int row = l & 31;
    int col = f*16 + ((l >> 5) << 3) + j;
    wfimg[e] = (f16)((row == 0) ? gWf[dd*kH + pif(col)] : 0.f);
  }
  cvt_img<24, kE , 0>(fcW0, fW0img, 1, t0, stride);
  cvt_img<32, kH , 1>(fcW1, fW1img, 1, t0, stride);
  cvt_img<32, kH , 1>(fcWf, fWfimg, 1, t0, stride);
  for (int i = t0; i < kD*kH; i += stride)
    w144buf[i] = gW0[(size_t)i*kFG + 144];
  if (t0 < kB) logdet[t0] = 0.f;
}

// ===== fc_mlp: emb(N,96) -> embh'(N,128) f16 (pi-ordered); 1 barrier ========
__global__ __launch_bounds__(256, 2) void fc_kernel(
    const float* __restrict__ emb,
    const f16* __restrict__ fW0, const f16* __restrict__ fW1,
    const f16* __restrict__ fWf,
    const float* __restrict__ b0, const float* __restrict__ b1,
    const float* __restrict__ bf, f16* __restrict__ out)
{
  __shared__ f16 wbuf[62*512];                 // fW1 frags 0..31, fWf frags 0..29
  const int bn = blockIdx.x * 128;
  const int tid = threadIdx.x, wave = tid >> 6, lane = tid & 63;
  const int l31 = lane & 31, h5 = lane >> 5;
  const int n = bn + wave*32 + l31;

  #pragma unroll
  for (int i = 0; i < 8; ++i)
    *(f16x8*)(wbuf + (size_t)(tid + i*256)*8) =
        *(const f16x8*)(fW1 + (size_t)(tid + i*256)*8);
  #pragma unroll
  for (int i = 0; i < 8; ++i) {
    int idx = tid + i*256;
    if (idx < 1920)
      *(f16x8*)(wbuf + (size_t)(2048 + idx)*8) =
          *(const f16x8*)(fWf + (size_t)idx*8);
  }

  const float* erow = emb + (size_t)n*kE + h5*8;
  f16x8 eB[6];
  #pragma unroll
  for (int c = 0; c < 6; ++c) {
    float4 a = *(const float4*)(erow + c*16);
    float4 bb = *(const float4*)(erow + c*16 + 4);
    f16x8 v;
    v[0]=(f16)a.x; v[1]=(f16)a.y; v[2]=(f16)a.z; v[3]=(f16)a.w;
    v[4]=(f16)bb.x; v[5]=(f16)bb.y; v[6]=(f16)bb.z; v[7]=(f16)bb.w;
    eB[c] = v;
  }
  __syncthreads();                              // B1: wbuf ready

  f32x16 zero = {};
  f32x16 acc[4] = {zero, zero, zero, zero};
  #pragma unroll
  for (int c = 0; c < 6; ++c)
    #pragma unroll
    for (int t = 0; t < 4; ++t)
      acc[t] = MFMA_(gfrag(fW0, c*4+t, lane), eB[c], acc[t], 0, 0, 0);

  f16x8 hq[4][2];
  #pragma unroll
  for (int t = 0; t < 4; ++t)
    #pragma unroll
    for (int q = 0; q < 4; ++q) {
      float4 b4 = *(const float4*)(b0 + t*32 + q*8 + h5*4);
      const float* bp = (const float*)&b4;
      #pragma unroll
      for (int e = 0; e < 4; ++e) {
        float z = acc[t][q*4+e] + bp[e];
        hq[t][q>>1][(q&1)*4+e] = (f16)fmaxf(z, SLOPE_*z);
      }
    }

  #pragma unroll
  for (int t = 0; t < 4; ++t) acc[t] = zero;
  #pragma unroll
  for (int c = 0; c < 8; ++c) {
    f16x8 bP = hq[c>>1][c&1];
    #pragma unroll
    for (int t = 0; t < 4; ++t)
      acc[t] = MFMA_(*(const f16x8*)(wbuf + (size_t)(c*4+t)*512 + lane*8),
                     bP, acc[t], 0, 0, 0);
  }
  #pragma unroll
  for (int t = 0; t < 4; ++t)
    #pragma unroll
    for (int q = 0; q < 4; ++q) {
      float4 b4 = *(const float4*)(b1 + t*32 + q*8 + h5*4);
      const float* bp = (const float*)&b4;
      #pragma unroll
      for (int e = 0; e < 4; ++e) {
        float z = acc[t][q*4+e] + bp[e];
        hq[t][q>>1][(q&1)*4+e] = (f16)fmaxf(z, SLOPE_*z);
      }
    }

  #pragma unroll
  for (int t = 0; t < 4; ++t) acc[t] = zero;
  #pragma unroll
  for (int c = 0; c < 8; ++c) {
    f16x8 bP = hq[c>>1][c&1];
    #pragma unroll
    for (int t = 0; t < 4; ++t) {
      int f = c*4 + t;
      f16x8 a = (f < 30) ? *(const f16x8*)(wbuf + (size_t)(32 + f)*512 + lane*8)
                         : gfrag(fWf, f, lane);
      acc[t] = MFMA_(a, bP, acc[t], 0, 0, 0);
    }
  }
  #pragma unroll
  for (int t = 0; t < 4; ++t)
    #pragma unroll
    for (int q = 0; q < 4; ++q) {
      float4 b4 = *(const float4*)(bf + t*32 + q*8 + h5*4);
      const float* bp = (const float*)&b4;
      #pragma unroll
      for (int e = 0; e < 4; ++e)
        hq[t][q>>1][(q&1)*4+e] = (f16)(acc[t][q*4+e] + bp[e]);
    }
  #pragma unroll
  for (int c = 0; c < 8; ++c)
    *(f16x8*)(out + (size_t)n*kH + c*16 + h5*8) = hq[c>>1][c&1];
}

// ==== g_mlp fwd + JVP: R6 structure, bias/xx/wf-dot moved into MFMA =========
// Block = 128 rows x one d, 4 waves x 32 rows x all cols. 2 waves/SIMD by
// design (128 VGPR + 128 AGPR); W1+W2 fully staged in 72 KB LDS; 2 barriers.
__global__ __launch_bounds__(256, 2) void g_kernel(
    const float* __restrict__ x, const f16* __restrict__ embh,
    const f16* __restrict__ W0img, const f16* __restrict__ W1img,
    const f16* __restrict__ W2img, const f16* __restrict__ wfimg,
    const float* __restrict__ w144buf, const float* __restrict__ gbf,
    float* __restrict__ resid, float* __restrict__ logdet)
{
  __shared__ f16 wbuf[72*512];                 // W1 frags 0..35, W2 frags 36..71
  __shared__ float part[8];
  const int d = blockIdx.y, bx = blockIdx.x, bn = bx*128;
  const int tid = threadIdx.x, wave = tid >> 6, lane = tid & 63;
  const int l31 = lane & 31, h5 = lane >> 5;
  const int n = bn + wave*32 + l31;
  const int b = n / kTM, tt = n - b*kTM;

  const f16* W0d = W0img + (size_t)d*40*512;
  const f16* W1d = W1img + (size_t)d*36*512;
  const f16* W2d = W2img + (size_t)d*36*512;
  const f16* WFd = wfimg + (size_t)d*8*512;

  // stage W1 (2304 units) + W2 (2304 units)
  #pragma unroll
  for (int i = 0; i < 9; ++i)
    *(f16x8*)(wbuf + (size_t)(tid + i*256)*8) =
        *(const f16x8*)(W1d + (size_t)(tid + i*256)*8);
  #pragma unroll
  for (int i = 0; i < 9; ++i)
    *(f16x8*)(wbuf + (size_t)(36*512) + (size_t)(tid + i*256)*8) =
        *(const f16x8*)(W2d + (size_t)(tid + i*256)*8);

  // x-derived inputs
  const float* xp = x + ((size_t)b*kT + tt + h5)*kD;
  float4 xa = *(const float4*)xp;
  float4 xb = *(const float4*)(xp + 4);
  f16x8 f8;
  f8[0]=(f16)xa.x; f8[1]=(f16)xa.y; f8[2]=(f16)xa.z; f8[3]=(f16)xa.w;
  f8[4]=(f16)xb.x; f8[5]=(f16)xb.y; f8[6]=(f16)xb.z; f8[7]=(f16)xb.w;
  const float xxv = x[((size_t)b*kT + tt + 2)*kD + d];
  f16x8 zeroh = {};
  f16x8 xb9 = zeroh;                 // chunk 9: [xx, 1, 0...] on h5==0 lanes
  if (!h5) { xb9[0] = (f16)xxv; xb9[1] = (f16)1.f; }
  f16x8 bC = zeroh;                  // bias chunk: [1, 0...] on h5==0 lanes
  if (!h5) bC[0] = (f16)1.f;

  f32x16 zero = {};
  f32x16 accP[4] = {zero, zero, zero, zero};

  // ---- P L0 (W0 direct-global, 40 frags; xx & b0 included via chunk 9)
  const f16* erow = embh + (size_t)n*kH + h5*8;
  #pragma unroll
  for (int c = 0; c < 8; ++c) {
    f16x8 eF = *(const f16x8*)(erow + c*16);
    #pragma unroll
    for (int t = 0; t < 4; ++t)
      accP[t] = MFMA_(gfrag(W0d, c*4+t, lane), eF, accP[t], 0, 0, 0);
  }
  #pragma unroll
  for (int t = 0; t < 4; ++t)
    accP[t] = MFMA_(gfrag(W0d, 32+t, lane), f8, accP[t], 0, 0, 0);
  #pragma unroll
  for (int t = 0; t < 4; ++t)
    accP[t] = MFMA_(gfrag(W0d, 36+t, lane), xb9, accP[t], 0, 0, 0);

  // L0 epilogue: z complete in acc; tangent seed = mask * w144
  f16x8 hqP[4][2], hqT[4][2];
  #pragma unroll
  for (int t = 0; t < 4; ++t)
    #pragma unroll
    for (int q = 0; q < 4; ++q) {
      float4 w4 = *(const float4*)(w144buf + d*kH + t*32 + q*8 + h5*4);
      const float* wp = (const float*)&w4;
      #pragma unroll
      for (int e = 0; e < 4; ++e) {
        float z = accP[t][q*4+e];
        bool pos = (z >= 0.f);
        hqP[t][q>>1][(q&1)*4+e] = (f16)(pos ? z : SLOPE_*z);
        hqT[t][q>>1][(q&1)*4+e] = (f16)(pos ? wp[e] : SLOPE_*wp[e]);
      }
    }
  __syncthreads();                              // B1: wbuf ready

  // ---- L1 (LDS frags 0..35; bias via chunk 8, P only)
  f32x16 accT[4] = {zero, zero, zero, zero};
  #pragma unroll
  for (int t = 0; t < 4; ++t) accP[t] = zero;
  #pragma unroll
  for (int c = 0; c < 9; ++c) {
    f16x8 bP = (c < 8) ? hqP[c>>1][c&1] : bC;
    #pragma unroll
    for (int t = 0; t < 4; ++t) {
      f16x8 a = *(const f16x8*)(wbuf + (size_t)(c*4+t)*512 + lane*8);
      accP[t] = MFMA_(a, bP, accP[t], 0, 0, 0);
      if (c < 8) {
        f16x8 bT = hqT[c>>1][c&1];
        accT[t] = MFMA_(a, bT, accT[t], 0, 0, 0);
      }
    }
  }
  #pragma unroll
  for (int t = 0; t < 4; ++t)
    #pragma unroll
    for (int q = 0; q < 4; ++q)
      #pragma unroll
      for (int e = 0; e < 4; ++e) {
        float z = accP[t][q*4+e];
        float tv = accT[t][q*4+e];
        bool pos = (z >= 0.f);
        hqP[t][q>>1][(q&1)*4+e] = (f16)(pos ? z : SLOPE_*z);
        hqT[t][q>>1][(q&1)*4+e] = (f16)(pos ? tv : SLOPE_*tv);
      }

  // ---- L2 (LDS frags 36..71; bias via chunk 8, P only)
  #pragma unroll
  for (int t = 0; t < 4; ++t) { accP[t] = zero; accT[t] = zero; }
  #pragma unroll
  for (int c = 0; c < 9; ++c) {
    f16x8 bP = (c < 8) ? hqP[c>>1][c&1] : bC;
    #pragma unroll
    for (int t = 0; t < 4; ++t) {
      f16x8 a = *(const f16x8*)(wbuf + (size_t)(36 + c*4+t)*512 + lane*8);
      accP[t] = MFMA_(a, bP, accP[t], 0, 0, 0);
      if (c < 8) {
        f16x8 bT = hqT[c>>1][c&1];
        accT[t] = MFMA_(a, bT, accT[t], 0, 0, 0);
      }
    }
  }
  #pragma unroll
  for (int t = 0; t < 4; ++t)
    #pragma unroll
    for (int q = 0; q < 4; ++q)
      #pragma unroll
      for (int e = 0; e < 4; ++e) {
        float z = accP[t][q*4+e];
        float tv = accT[t][q*4+e];
        bool pos = (z >= 0.f);
        hqP[t][q>>1][(q&1)*4+e] = (f16)(pos ? z : SLOPE_*z);
        hqT[t][q>>1][(q&1)*4+e] = (f16)(pos ? tv : SLOPE_*tv);
      }

  // ---- final dots via MFMA (wf in output-row 0 of wfimg)
  accP[0] = zero; accT[0] = zero;
  #pragma unroll
  for (int c = 0; c < 8; ++c) {
    f16x8 wff = gfrag(WFd, c, lane);
    accP[0] = MFMA_(wff, hqP[c>>1][c&1], accP[0], 0, 0, 0);
    accT[0] = MFMA_(wff, hqT[c>>1][c&1], accT[0], 0, 0, 0);
  }
  // row 0 result lives in reg 0 of lanes 0..31 (col = lane)
  float llog = 0.f;
  if (!h5) {
    float p  = accP[0][0];
    float tp = accT[0][0];
    resid[(size_t)n*kD + d] = p + gbf[d];
    llog = logf(fabsf(tp));
  }
  const int bfirst = bn / kTM;
  float s0 = (b == bfirst) ? llog : 0.f;
  float s1 = llog - s0;
  #pragma unroll
  for (int off = 32; off > 0; off >>= 1) {
    s0 += __shfl_down(s0, off, 64);
    s1 += __shfl_down(s1, off, 64);
  }
  if (lane == 0) { part[wave*2] = s0; part[wave*2 + 1] = s1; }
  __syncthreads();                              // B2
  if (tid == 0) {
    float S0 = part[0] + part[2] + part[4] + part[6];
    float S1 = part[1] + part[3] + part[5] + part[7];
    atomicAdd(&logdet[bfirst], S0);
    if (S1 != 0.f) atomicAdd(&logdet[bfirst + 1], S1);
  }
}

extern "C" void kernel_launch(void* const* d_in, const int* in_sizes, int n_in,
                              void* d_out, int out_size, void* d_ws, size_t ws_size,
                              hipStream_t stream) {
  const float* x    = (const float*)d_in[0];
  const float* emb  = (const float*)d_in[1];
  const float* fcW0 = (const float*)d_in[2];
  const float* fcb0 = (const float*)d_in[3];
  const float* fcW1 = (const float*)d_in[4];
  const float* fcb1 = (const float*)d_in[5];
  const float* fcWf = (const float*)d_in[6];
  const float* fcbf = (const float*)d_in[7];
  const float* gW0  = (const float*)d_in[8];
  const float* gb0  = (const float*)d_in[9];
  const float* gW1  = (const float*)d_in[10];
  const float* gb1  = (const float*)d_in[11];
  const float* gW2  = (const float*)d_in[12];
  const float* gb2  = (const float*)d_in[13];
  const float* gWf  = (const float*)d_in[14];
  const float* gbf  = (const float*)d_in[15];
  float* out = (float*)d_out;
  float* logdet = out + (size_t)kN * kD;

  char* ws = (char*)d_ws;
  f16*   embh    = (f16*)ws;    ws += (size_t)kN*kH*2;
  f16*   W0img   = (f16*)ws;    ws += (size_t)kD*40*512*2;
  f16*   W1img   = (f16*)ws;    ws += (size_t)kD*36*512*2;
  f16*   W2img   = (f16*)ws;    ws += (size_t)kD*36*512*2;
  f16*   wfimg   = (f16*)ws;    ws += (size_t)kD*8*512*2;
  f16*   fW0img  = (f16*)ws;    ws += (size_t)24*512*2;
  f16*   fW1img  = (f16*)ws;    ws += (size_t)32*512*2;
  f16*   fWfimg  = (f16*)ws;    ws += (size_t)32*512*2;
  float* w144buf = (float*)ws;

  cvt_kernel<<<256, 256, 0, stream>>>(gW0, gW1, gW2, gb0, gb1, gb2, gWf,
                                      fcW0, fcW1, fcWf,
                                      W0img, W1img, W2img, wfimg,
                                      fW0img, fW1img, fWfimg,
                                      w144buf, logdet);
  fc_kernel<<<kN/128, 256, 0, stream>>>(emb, fW0img, fW1img, fWfimg,
                                        fcb0, fcb1, fcbf, embh);
  g_kernel<<<dim3(kN/128, kD), 256, 0, stream>>>(
      x, embh, W0img, W1img, W2img, wfimg, w144buf, gbf, out, logdet);
}